// Round 1
// baseline (280.629 us; speedup 1.0000x reference)
//
#include <hip/hip_runtime.h>

#define E_ 8
#define O_ 256
#define I_ 128
#define B_ 32
#define H_ 56
#define W_ 56
#define HP 58
#define HW (H_*W_)
#define KK 9

typedef __attribute__((ext_vector_type(8))) short short8;
typedef __attribute__((ext_vector_type(4))) float float4_;

// ws layout (bytes)
#define XP_ELEMS (B_*HP*HP*I_)              // 13,778,944 bf16
#define POOL_OFF ((size_t)XP_ELEMS*2)       // 27,557,888
#define R_OFF    (POOL_OFF + (size_t)B_*I_*4)
#define CWT_OFF  (R_OFF + (size_t)B_*E_*4)

__device__ __forceinline__ unsigned short f2bf(float f) {
  union { float f; unsigned u; } v; v.f = f;
  unsigned r = v.u + 0x7FFFu + ((v.u >> 16) & 1u);
  return (unsigned short)(r >> 16);
}

__device__ __forceinline__ void gload16(const unsigned short* g, unsigned short* l) {
  __builtin_amdgcn_global_load_lds(
      (const __attribute__((address_space(1))) unsigned int*)g,
      (__attribute__((address_space(3))) unsigned int*)l, 16, 0, 0);
}

// ---------------- K1: NCHW f32 -> padded NHWC bf16, + channel pooling ----------------
__global__ void k1_pool_pack(const float* __restrict__ x,
                             unsigned short* __restrict__ xp,
                             float* __restrict__ pooled) {
  __shared__ float lds[I_*57];
  const int h = blockIdx.x, b = blockIdx.y, tid = threadIdx.x;
  const float* xb = x + (size_t)b*I_*HW + h*W_;
  for (int idx = tid; idx < I_*W_; idx += 256) {
    int ic = idx / W_, wv = idx - ic*W_;
    lds[ic*57 + wv] = xb[(size_t)ic*HW + wv];
  }
  __syncthreads();
  if (tid < I_) {
    float s = 0.f;
    #pragma unroll 8
    for (int wv = 0; wv < W_; ++wv) s += lds[tid*57 + wv];
    atomicAdd(&pooled[b*I_ + tid], s);
  }
  unsigned short* xrow = xp + ((size_t)(b*HP + h + 1)*HP)*I_;
  for (int idx2 = tid; idx2 < W_*(I_/2); idx2 += 256) {
    int wv = idx2 >> 6, ic2 = idx2 & 63;
    unsigned short u0 = f2bf(lds[(ic2*2)*57 + wv]);
    unsigned short u1 = f2bf(lds[(ic2*2+1)*57 + wv]);
    *(unsigned*)&xrow[(wv+1)*I_ + ic2*2] = (unsigned)u0 | ((unsigned)u1 << 16);
  }
  if (tid < I_) {           // pad columns 0 and 57 of this row
    xrow[0*I_ + tid] = 0;
    xrow[57*I_ + tid] = 0;
  }
  if (h == 0) {             // pad row 0
    unsigned short* r0 = xp + (size_t)(b*HP)*HP*I_;
    for (int idx = tid; idx < HP*I_; idx += 256) r0[idx] = 0;
  }
  if (h == H_-1) {          // pad row 57
    unsigned short* r57 = xp + (size_t)((b*HP + 57)*HP)*I_;
    for (int idx = tid; idx < HP*I_; idx += 256) r57[idx] = 0;
  }
}

// ---------------- K2: routing MLP + softmax (fp32 exact) ----------------
__global__ void k2_route(const float* __restrict__ pooled,
                         const float* __restrict__ w1, const float* __restrict__ b1,
                         const float* __restrict__ w2, const float* __restrict__ b2,
                         float* __restrict__ r) {
  __shared__ float p[I_];
  __shared__ float hh[32];
  __shared__ float lg[8];
  const int b = blockIdx.x, tid = threadIdx.x;
  if (tid < 64) {
    p[tid]      = pooled[b*I_ + tid]      * (1.f/HW);
    p[tid + 64] = pooled[b*I_ + tid + 64] * (1.f/HW);
  }
  __syncthreads();
  if (tid < 32) {
    float s = b1[tid];
    for (int i = 0; i < I_; ++i) s += p[i]*w1[tid*I_ + i];
    hh[tid] = s > 0.f ? s : 0.f;
  }
  __syncthreads();
  if (tid < 8) {
    float s = b2[tid];
    for (int j = 0; j < 32; ++j) s += hh[j]*w2[tid*32 + j];
    lg[tid] = s;
  }
  __syncthreads();
  if (tid == 0) {
    float m = lg[0];
    for (int e = 1; e < 8; ++e) m = fmaxf(m, lg[e]);
    float ex[8], sum = 0.f;
    for (int e = 0; e < 8; ++e) { ex[e] = expf(lg[e]-m); sum += ex[e]; }
    float inv = 1.f/sum;
    for (int e = 0; e < 8; ++e) r[b*8 + e] = ex[e]*inv;
  }
}

// ---------------- K3: combine expert weights -> cwT[b][tap][o][ic] bf16 ----------------
__global__ void k3_combine(const float* __restrict__ weight, const float* __restrict__ r,
                           unsigned short* __restrict__ cwT) {
  __shared__ float wl[E_*1152];   // 36.9 KB
  const int o = blockIdx.x, tid = threadIdx.x;
  for (int e = 0; e < E_; ++e)
    for (int idx = tid; idx < 1152; idx += 256)
      wl[e*1152 + idx] = weight[(size_t)(e*O_ + o)*1152 + idx];
  __syncthreads();
  for (int b = 0; b < B_; ++b) {
    float rb[E_];
    #pragma unroll
    for (int e = 0; e < E_; ++e) rb[e] = r[b*E_ + e];
    for (int idx2 = tid; idx2 < 576; idx2 += 256) {
      int t = idx2 >> 6, ic2 = idx2 & 63;
      int ic = ic2*2;
      float v0 = 0.f, v1 = 0.f;
      #pragma unroll
      for (int e = 0; e < E_; ++e) {
        v0 += rb[e]*wl[e*1152 + ic*9 + t];
        v1 += rb[e]*wl[e*1152 + (ic+1)*9 + t];
      }
      *(unsigned*)&cwT[((size_t)(b*KK + t)*O_ + o)*I_ + ic] =
          (unsigned)f2bf(v0) | ((unsigned)f2bf(v1) << 16);
    }
  }
}

// ---------------- K4: main conv as 9-tap implicit GEMM, bf16 MFMA ----------------
// block tile: 128 out-channels x 128 pixels; 4 waves 2x2, wave tile 64x64 (4x4 frags)
__global__ __launch_bounds__(256)
void k4_conv(const unsigned short* __restrict__ xp,
             const unsigned short* __restrict__ cwT,
             const float* __restrict__ r, const float* __restrict__ bias,
             float* __restrict__ out) {
  __shared__ __align__(16) unsigned short ldsA[128*64];  // [m][k] swizzled, 16 KB
  __shared__ __align__(16) unsigned short ldsB[128*64];  // [n][k] swizzled, 16 KB
  __shared__ float cbs[128];

  const int tid  = threadIdx.x;
  const int lane = tid & 63;
  const int wave = tid >> 6;
  const int n0 = blockIdx.x * 128;
  const int m0 = blockIdx.y * 128;
  const int b  = blockIdx.z;

  if (tid < 128) {
    float s = 0.f;
    #pragma unroll
    for (int e = 0; e < 8; ++e) s += r[b*8 + e]*bias[e*O_ + m0 + tid];
    cbs[tid] = s;
  }

  const int q = lane >> 4, l16 = lane & 15;
  const int lrow = lane >> 3, lchk = lane & 7;
  const int chunk = lchk ^ lrow;        // XOR-swizzled global chunk this lane fetches
  const int wm0 = (wave >> 1) * 64;
  const int wn0 = (wave & 1) * 64;

  // per-thread invariant load offsets
  int ainv[4], binv[4];
  #pragma unroll
  for (int j = 0; j < 4; ++j) {
    int row = wave*32 + j*8 + lrow;
    ainv[j] = row*I_ + chunk*8;
    int p = n0 + (wave + 4*j)*8 + lrow;
    int pc = p < HW ? p : HW-1;
    int rj = pc / 56, wj = pc - rj*56;
    binv[j] = ((b*HP + rj)*HP + wj)*I_ + chunk*8;
  }
  // fragment LDS read offsets (ushort units)
  int xq[2], rowA[4], rowB[4];
  #pragma unroll
  for (int s = 0; s < 2; ++s) xq[s] = ((s*4 + q) ^ (l16 & 7))*8;
  #pragma unroll
  for (int f = 0; f < 4; ++f) rowA[f] = (wm0 + f*16 + l16)*64;
  #pragma unroll
  for (int g = 0; g < 4; ++g) rowB[g] = (wn0 + g*16 + l16)*64;

  float4_ acc[4][4];
  #pragma unroll
  for (int f = 0; f < 4; ++f)
    #pragma unroll
    for (int g = 0; g < 4; ++g) acc[f][g] = (float4_){0.f, 0.f, 0.f, 0.f};

  for (int kh = 0; kh < 3; ++kh)
  for (int kw = 0; kw < 3; ++kw) {
    const int tap = kh*3 + kw;
    #pragma unroll
    for (int icc = 0; icc < 2; ++icc) {
      __syncthreads();
      const unsigned short* abase = cwT + (((size_t)(b*KK + tap)*O_ + m0)*I_ + icc*64);
      #pragma unroll
      for (int j = 0; j < 4; ++j)
        gload16(abase + ainv[j], &ldsA[(wave*32 + j*8)*64]);
      const unsigned short* bbase = xp + ((kh*HP + kw)*I_ + icc*64);
      #pragma unroll
      for (int j = 0; j < 4; ++j)
        gload16(bbase + binv[j], &ldsB[((wave + 4*j)*8)*64]);
      __syncthreads();
      #pragma unroll
      for (int s = 0; s < 2; ++s) {
        short8 af[4], bfr[4];
        #pragma unroll
        for (int f = 0; f < 4; ++f) af[f] = *(const short8*)&ldsA[rowA[f] + xq[s]];
        #pragma unroll
        for (int g = 0; g < 4; ++g) bfr[g] = *(const short8*)&ldsB[rowB[g] + xq[s]];
        #pragma unroll
        for (int f = 0; f < 4; ++f)
          #pragma unroll
          for (int g = 0; g < 4; ++g)
            acc[f][g] = __builtin_amdgcn_mfma_f32_16x16x32_bf16(af[f], bfr[g], acc[f][g], 0, 0, 0);
      }
    }
  }

  // epilogue: D row(m)=quad*4+reg, col(n)=lane&15  [m89-verified layout]
  #pragma unroll
  for (int g = 0; g < 4; ++g) {
    int p = n0 + wn0 + g*16 + l16;
    if (p < HW) {
      #pragma unroll
      for (int f = 0; f < 4; ++f) {
        #pragma unroll
        for (int v = 0; v < 4; ++v) {
          int ml = wm0 + f*16 + q*4 + v;
          out[(size_t)(b*O_ + m0 + ml)*HW + p] = acc[f][g][v] + cbs[ml];
        }
      }
    }
  }
}

extern "C" void kernel_launch(void* const* d_in, const int* in_sizes, int n_in,
                              void* d_out, int out_size, void* d_ws, size_t ws_size,
                              hipStream_t stream) {
  const float* x      = (const float*)d_in[0];
  const float* weight = (const float*)d_in[1];
  const float* bias   = (const float*)d_in[2];
  const float* w1     = (const float*)d_in[3];
  const float* b1     = (const float*)d_in[4];
  const float* w2     = (const float*)d_in[5];
  const float* b2     = (const float*)d_in[6];
  float* out = (float*)d_out;
  char* ws = (char*)d_ws;

  unsigned short* xp     = (unsigned short*)(ws);
  float*          pooled = (float*)(ws + POOL_OFF);
  float*          rr     = (float*)(ws + R_OFF);
  unsigned short* cwT    = (unsigned short*)(ws + CWT_OFF);

  hipMemsetAsync(pooled, 0, B_*I_*sizeof(float), stream);
  k1_pool_pack<<<dim3(H_, B_), 256, 0, stream>>>(x, xp, pooled);
  k2_route<<<B_, 64, 0, stream>>>(pooled, w1, b1, w2, b2, rr);
  k3_combine<<<O_, 256, 0, stream>>>(weight, rr, cwT);
  k4_conv<<<dim3(25, 2, B_), 256, 0, stream>>>(xp, cwT, rr, bias, out);
}

// Round 2
// 258.410 us; speedup vs baseline: 1.0860x; 1.0860x over previous
//
#include <hip/hip_runtime.h>

#define E_ 8
#define O_ 256
#define I_ 128
#define B_ 32
#define H_ 56
#define W_ 56
#define HP 58
#define HW (H_*W_)
#define KK 9

#define NROW 4          // pixel rows per n-tile
#define NPIX 224        // NROW*56
#define PPIX 348        // (NROW+2)*58 patch pixels

typedef __attribute__((ext_vector_type(8))) short short8;
typedef __attribute__((ext_vector_type(4))) float float4_;

// ws layout (bytes)
#define XP_ELEMS (B_*HP*HP*I_)                   // padded NHWC bf16
#define POOL_OFF ((size_t)XP_ELEMS*2)            // 27,557,888
#define R_OFF    (POOL_OFF + (size_t)B_*H_*I_*4) // pooled_part: 917,504 B
#define CWT_OFF  (R_OFF + (size_t)B_*E_*4)

__device__ __forceinline__ unsigned short f2bf(float f) {
  union { float f; unsigned u; } v; v.f = f;
  unsigned r = v.u + 0x7FFFu + ((v.u >> 16) & 1u);
  return (unsigned short)(r >> 16);
}

__device__ __forceinline__ void gload16(const unsigned short* g, unsigned short* l) {
  __builtin_amdgcn_global_load_lds(
      (const __attribute__((address_space(1))) unsigned int*)g,
      (__attribute__((address_space(3))) unsigned int*)l, 16, 0, 0);
}

// ---------------- K1: NCHW f32 -> padded NHWC bf16, + per-row channel sums ----------------
__global__ void k1_pool_pack(const float* __restrict__ x,
                             unsigned short* __restrict__ xp,
                             float* __restrict__ pooled_part) {
  __shared__ float lds[I_*57];
  const int h = blockIdx.x, b = blockIdx.y, tid = threadIdx.x;
  const float* xb = x + (size_t)b*I_*HW + h*W_;
  for (int idx = tid; idx < I_*W_; idx += 256) {
    int ic = idx / W_, wv = idx - ic*W_;
    lds[ic*57 + wv] = xb[(size_t)ic*HW + wv];
  }
  __syncthreads();
  if (tid < I_) {
    float s = 0.f;
    #pragma unroll 8
    for (int wv = 0; wv < W_; ++wv) s += lds[tid*57 + wv];
    pooled_part[(size_t)(b*H_ + h)*I_ + tid] = s;   // no atomics, no memset
  }
  unsigned short* xrow = xp + ((size_t)(b*HP + h + 1)*HP)*I_;
  for (int idx2 = tid; idx2 < W_*(I_/2); idx2 += 256) {
    int wv = idx2 >> 6, ic2 = idx2 & 63;
    unsigned short u0 = f2bf(lds[(ic2*2)*57 + wv]);
    unsigned short u1 = f2bf(lds[(ic2*2+1)*57 + wv]);
    *(unsigned*)&xrow[(wv+1)*I_ + ic2*2] = (unsigned)u0 | ((unsigned)u1 << 16);
  }
  if (tid < I_) {           // pad columns 0 and 57 of this row
    xrow[0*I_ + tid] = 0;
    xrow[57*I_ + tid] = 0;
  }
  if (h == 0) {             // pad row 0
    unsigned short* r0 = xp + (size_t)(b*HP)*HP*I_;
    for (int idx = tid; idx < HP*I_; idx += 256) r0[idx] = 0;
  }
  if (h == H_-1) {          // pad row 57
    unsigned short* r57 = xp + (size_t)((b*HP + 57)*HP)*I_;
    for (int idx = tid; idx < HP*I_; idx += 256) r57[idx] = 0;
  }
}

// ---------------- K2: reduce partials + routing MLP + softmax (fp32 exact) ----------------
__global__ void k2_route(const float* __restrict__ pooled_part,
                         const float* __restrict__ w1, const float* __restrict__ b1,
                         const float* __restrict__ w2, const float* __restrict__ b2,
                         float* __restrict__ r) {
  __shared__ float p[I_];
  __shared__ float hh[32];
  __shared__ float lg[8];
  const int b = blockIdx.x, tid = threadIdx.x;
  if (tid < I_) {
    float s = 0.f;
    for (int h = 0; h < H_; ++h) s += pooled_part[(size_t)(b*H_ + h)*I_ + tid];
    p[tid] = s * (1.f/HW);
  }
  __syncthreads();
  if (tid < 32) {
    float s = b1[tid];
    for (int i = 0; i < I_; ++i) s += p[i]*w1[tid*I_ + i];
    hh[tid] = s > 0.f ? s : 0.f;
  }
  __syncthreads();
  if (tid < 8) {
    float s = b2[tid];
    for (int j = 0; j < 32; ++j) s += hh[j]*w2[tid*32 + j];
    lg[tid] = s;
  }
  __syncthreads();
  if (tid == 0) {
    float m = lg[0];
    for (int e = 1; e < 8; ++e) m = fmaxf(m, lg[e]);
    float ex[8], sum = 0.f;
    for (int e = 0; e < 8; ++e) { ex[e] = expf(lg[e]-m); sum += ex[e]; }
    float inv = 1.f/sum;
    for (int e = 0; e < 8; ++e) r[b*8 + e] = ex[e]*inv;
  }
}

// ---------------- K3: combine expert weights -> cwT[b][tap][o][ic] bf16 ----------------
__global__ void k3_combine(const float* __restrict__ weight, const float* __restrict__ r,
                           unsigned short* __restrict__ cwT) {
  __shared__ float wl[E_*1152];   // 36.9 KB
  const int o = blockIdx.x, tid = threadIdx.x;
  const int b0 = blockIdx.y * 16;
  for (int e = 0; e < E_; ++e)
    for (int idx = tid; idx < 1152; idx += 256)
      wl[e*1152 + idx] = weight[(size_t)(e*O_ + o)*1152 + idx];
  __syncthreads();
  for (int b = b0; b < b0 + 16; ++b) {
    float rb[E_];
    #pragma unroll
    for (int e = 0; e < E_; ++e) rb[e] = r[b*E_ + e];
    for (int idx2 = tid; idx2 < 576; idx2 += 256) {
      int t = idx2 >> 6, ic2 = idx2 & 63;
      int ic = ic2*2;
      float v0 = 0.f, v1 = 0.f;
      #pragma unroll
      for (int e = 0; e < E_; ++e) {
        v0 += rb[e]*wl[e*1152 + ic*9 + t];
        v1 += rb[e]*wl[e*1152 + (ic+1)*9 + t];
      }
      *(unsigned*)&cwT[((size_t)(b*KK + t)*O_ + o)*I_ + ic] =
          (unsigned)f2bf(v0) | ((unsigned)f2bf(v1) << 16);
    }
  }
}

// ---------------- K4: halo-patch implicit GEMM, bf16 MFMA ----------------
// block: 128 out-ch x 224 pixels (4 rows), b fixed. 4 waves 2x2, wave 64x112 (4x7 frags).
// LDS: pixel patch staged once per ic-chunk; 16KB weight tile double-buffered, 1 barrier/tap.
__global__ __launch_bounds__(256, 2)
void k4_conv(const unsigned short* __restrict__ xp,
             const unsigned short* __restrict__ cwT,
             const float* __restrict__ r, const float* __restrict__ bias,
             float* __restrict__ out) {
  __shared__ __align__(16) unsigned short patch[PPIX*64];     // 43.5 KB, XOR-swizzled
  __shared__ __align__(16) unsigned short ldsA[2][128*64];    // 2 x 16 KB
  __shared__ float cbs[128];

  const int tid  = threadIdx.x;
  const int lane = tid & 63;
  const int wave = tid >> 6;
  const int gr0 = blockIdx.x * NROW;      // first pixel row of tile
  const int m0  = blockIdx.y * 128;
  const int b   = blockIdx.z;

  if (tid < 128) {
    float s = 0.f;
    #pragma unroll
    for (int e = 0; e < 8; ++e) s += r[b*8 + e]*bias[e*O_ + m0 + tid];
    cbs[tid] = s;
  }

  const int q = lane >> 4, l16 = lane & 15;
  const int lrow = lane >> 3, chunk = (lane & 7) ^ lrow;
  const int wm0 = (wave >> 1) * 64;
  const int wn0 = (wave & 1) * 112;

  int ainv[4];
  #pragma unroll
  for (int j = 0; j < 4; ++j)
    ainv[j] = (wave*32 + j*8 + lrow)*I_ + chunk*8;
  int rowA[4];
  #pragma unroll
  for (int f = 0; f < 4; ++f) rowA[f] = (wm0 + f*16 + l16)*64;
  int xq[2];
  #pragma unroll
  for (int s = 0; s < 2; ++s) xq[s] = ((s*4 + q) ^ (l16 & 7))*8;
  int bg[7];
  #pragma unroll
  for (int g = 0; g < 7; ++g) {
    int p = wn0 + g*16 + l16;
    int rr_ = p / 56;
    bg[g] = rr_*58 + (p - rr_*56);
  }

  float4_ acc[4][7];
  #pragma unroll
  for (int f = 0; f < 4; ++f)
    #pragma unroll
    for (int g = 0; g < 7; ++g) acc[f][g] = (float4_){0.f, 0.f, 0.f, 0.f};

  const unsigned short* xpb = xp + (size_t)((b*HP + gr0)*HP)*I_;

  for (int icc = 0; icc < 2; ++icc) {
    __syncthreads();   // patch + both A buffers free
    // stage halo patch (6x58 pixels x 64 ic), XOR-swizzled k8 groups
    for (int it = 0; it < 11; ++it) {
      int c = it*256 + tid;
      if (c < PPIX*8) {
        int pp = c >> 3, k8 = c & 7;
        short8 v = *(const short8*)(xpb + (size_t)pp*I_ + icc*64 + k8*8);
        *(short8*)&patch[pp*64 + ((k8 ^ (pp & 7))*8)] = v;
      }
    }
    // stage A for tap 0
    {
      const unsigned short* ab = cwT + ((size_t)(b*KK)*O_ + m0)*I_ + icc*64;
      #pragma unroll
      for (int j = 0; j < 4; ++j)
        gload16(ab + ainv[j], &ldsA[0][(wave*32 + j*8)*64]);
    }
    for (int tap = 0; tap < 9; ++tap) {
      __syncthreads();   // publishes A[tap] (and patch on tap==0)
      if (tap < 8) {     // prefetch A[tap+1] into the other buffer
        const unsigned short* ab = cwT + ((size_t)(b*KK + tap + 1)*O_ + m0)*I_ + icc*64;
        #pragma unroll
        for (int j = 0; j < 4; ++j)
          gload16(ab + ainv[j], &ldsA[(tap + 1) & 1][(wave*32 + j*8)*64]);
      }
      const unsigned short* At = ldsA[tap & 1];
      const int kh = tap / 3, kw = tap - kh*3;
      const int toff = kh*58 + kw;
      #pragma unroll
      for (int s = 0; s < 2; ++s) {
        short8 af[4], bfr[7];
        #pragma unroll
        for (int f = 0; f < 4; ++f) af[f] = *(const short8*)&At[rowA[f] + xq[s]];
        #pragma unroll
        for (int g = 0; g < 7; ++g) {
          int pp = bg[g] + toff;
          bfr[g] = *(const short8*)&patch[pp*64 + (((s*4 + q) ^ (pp & 7))*8)];
        }
        #pragma unroll
        for (int f = 0; f < 4; ++f)
          #pragma unroll
          for (int g = 0; g < 7; ++g)
            acc[f][g] = __builtin_amdgcn_mfma_f32_16x16x32_bf16(af[f], bfr[g], acc[f][g], 0, 0, 0);
      }
    }
  }

  // epilogue: D row(m)=quad*4+reg, col(n)=lane&15
  const size_t obase = (size_t)(b*O_ + m0)*HW + gr0*W_;
  #pragma unroll
  for (int g = 0; g < 7; ++g) {
    int p = wn0 + g*16 + l16;          // tile-local pixel, always < 224
    #pragma unroll
    for (int f = 0; f < 4; ++f) {
      #pragma unroll
      for (int v = 0; v < 4; ++v) {
        int ml = wm0 + f*16 + q*4 + v;
        out[obase + (size_t)ml*HW + p] = acc[f][g][v] + cbs[ml];
      }
    }
  }
}

extern "C" void kernel_launch(void* const* d_in, const int* in_sizes, int n_in,
                              void* d_out, int out_size, void* d_ws, size_t ws_size,
                              hipStream_t stream) {
  const float* x      = (const float*)d_in[0];
  const float* weight = (const float*)d_in[1];
  const float* bias   = (const float*)d_in[2];
  const float* w1     = (const float*)d_in[3];
  const float* b1     = (const float*)d_in[4];
  const float* w2     = (const float*)d_in[5];
  const float* b2     = (const float*)d_in[6];
  float* out = (float*)d_out;
  char* ws = (char*)d_ws;

  unsigned short* xp     = (unsigned short*)(ws);
  float*          ppart  = (float*)(ws + POOL_OFF);
  float*          rr     = (float*)(ws + R_OFF);
  unsigned short* cwT    = (unsigned short*)(ws + CWT_OFF);

  k1_pool_pack<<<dim3(H_, B_), 256, 0, stream>>>(x, xp, ppart);
  k2_route<<<B_, 128, 0, stream>>>(ppart, w1, b1, w2, b2, rr);
  k3_combine<<<dim3(O_, 2), 256, 0, stream>>>(weight, rr, cwT);
  k4_conv<<<dim3(H_/NROW, 2, B_), 256, 0, stream>>>(xp, cwT, rr, bias, out);
}